// Round 1
// baseline (251.774 us; speedup 1.0000x reference)
//
#include <hip/hip_runtime.h>

// Biaffine: out[b,x,y] = sum_ij Daug[b,x,i] U[i,j] H[b,y,j] + Daug[b,x,:].W[:d+1] + H[b,y,:].W[d+1:]
// B=32, S=512, d=1024.  Strategy: bf16 MFMA two-stage GEMM.
//   T = D @ U[0:d,:] + U[d,:]           (16384 x 1024 x 1024 GEMM + bias)
//   out[b] = T[b] @ H[b]^T + linD + linH (32 batched 512x512x1024 GEMMs)
// linD = D.W[0:d] + W[d], linH = H.W[d+1:2d+1]  (fp32, fused into cast kernel)

#define D_DIM 1024
#define ROWS 16384   // B*S

typedef float floatx4 __attribute__((ext_vector_type(4)));
typedef __bf16 bf16x8 __attribute__((ext_vector_type(8)));

__device__ inline unsigned short f2bf(float f) {
  unsigned int u = __builtin_bit_cast(unsigned int, f);
  u = (u + 0x7FFFu + ((u >> 16) & 1u)) >> 16;   // round-nearest-even
  return (unsigned short)u;
}

__device__ inline void async_load16(const void* g, void* l) {
  __builtin_amdgcn_global_load_lds(
      (const __attribute__((address_space(1))) void*)g,
      (__attribute__((address_space(3))) void*)l, 16, 0, 0);
}

// ---- cast D/H to bf16 + fused linear-term dot products ----------------------
__global__ __launch_bounds__(256) void cast_rows_kernel(
    const float* __restrict__ D, const float* __restrict__ H,
    const float* __restrict__ W,
    unsigned short* __restrict__ Dbf, unsigned short* __restrict__ Hbf,
    float* __restrict__ linD, float* __restrict__ linH) {
  int rowid = blockIdx.x;
  bool isH = rowid >= ROWS;
  int r = isH ? rowid - ROWS : rowid;
  const float* src = (isH ? H : D) + (size_t)r * D_DIM;
  unsigned short* dst = (isH ? Hbf : Dbf) + (size_t)r * D_DIM;
  const float* w = W + (isH ? (D_DIM + 1) : 0);
  int t = threadIdx.x;                 // 256 threads, 4 elems each
  float4 v = ((const float4*)src)[t];
  // w may be misaligned (offset 1025) -> scalar loads (L1-cached)
  float s = v.x * w[4*t] + v.y * w[4*t+1] + v.z * w[4*t+2] + v.w * w[4*t+3];
  ushort4 o;
  o.x = f2bf(v.x); o.y = f2bf(v.y); o.z = f2bf(v.z); o.w = f2bf(v.w);
  ((ushort4*)dst)[t] = o;
  #pragma unroll
  for (int off = 32; off > 0; off >>= 1) s += __shfl_down(s, off, 64);
  __shared__ float red[4];
  int wave = t >> 6;
  if ((t & 63) == 0) red[wave] = s;
  __syncthreads();
  if (t == 0) {
    float tot = red[0] + red[1] + red[2] + red[3];
    if (!isH) tot += W[D_DIM];         // ones-column bias for Daug side
    (isH ? linH : linD)[r] = tot;
  }
}

// ---- transpose U (first 1024 rows) to bf16 Ut[n][k] = U[k][n] ---------------
__global__ __launch_bounds__(256) void transU_kernel(
    const float* __restrict__ U, unsigned short* __restrict__ Ut) {
  __shared__ float tile[32][33];
  int n0 = blockIdx.x * 32;
  int k0 = blockIdx.y * 32;
  int t = threadIdx.x;
  int tr = t >> 5, tc = t & 31;
  #pragma unroll
  for (int i = 0; i < 32; i += 8)
    tile[tr + i][tc] = U[(size_t)(k0 + tr + i) * D_DIM + n0 + tc];
  __syncthreads();
  #pragma unroll
  for (int i = 0; i < 32; i += 8)
    Ut[(size_t)(n0 + tr + i) * D_DIM + k0 + tc] = f2bf(tile[tc][tr + i]);
}

// ---- GEMM1: T[m][n] = sum_k Dbf[m][k] * Ut[n][k] + Ubias[n], bf16 out -------
// m97 structure: 128x128 tile, BK=32, 4 waves (2x2 of 64x64), 16x16x32 MFMA,
// global_load_lds width=16 (LDS dest = wave-uniform base + lane*16 -> no pad).
__global__ __launch_bounds__(256) void gemm1_kernel(
    const unsigned short* __restrict__ A,    // [16384,1024] bf16 bits
    const unsigned short* __restrict__ Bt,   // [1024,1024]  bf16 bits
    const float* __restrict__ Ubias,         // U + 1024*1024 (fp32, len 1024)
    unsigned short* __restrict__ T) {
  __shared__ __align__(16) unsigned short As[128 * 32];
  __shared__ __align__(16) unsigned short Bs[128 * 32];
  const int K = D_DIM;
  int tid = threadIdx.x;
  int lane = tid & 63, wave = tid >> 6;
  int quad = lane >> 4, lrow = lane & 15;
  int wm = wave >> 1, wn = wave & 1;
  int m0 = blockIdx.y * 128, n0 = blockIdx.x * 128;

  floatx4 acc[4][4] = {};

  int cc0 = tid, cc1 = tid + 256;          // chunk ids, 16B each, 512 chunks/tile
  int r0 = cc0 >> 2, kc0 = (cc0 & 3) * 8;
  int r1 = cc1 >> 2, kc1 = (cc1 & 3) * 8;
  const unsigned short* gA0 = A + (size_t)(m0 + r0) * K + kc0;
  const unsigned short* gA1 = A + (size_t)(m0 + r1) * K + kc1;
  const unsigned short* gB0 = Bt + (size_t)(n0 + r0) * K + kc0;
  const unsigned short* gB1 = Bt + (size_t)(n0 + r1) * K + kc1;

  for (int k0 = 0; k0 < K; k0 += 32) {
    __syncthreads();                       // prior ds_reads done before overwrite
    async_load16(gA0 + k0, As + cc0 * 8);
    async_load16(gA1 + k0, As + cc1 * 8);
    async_load16(gB0 + k0, Bs + cc0 * 8);
    async_load16(gB1 + k0, Bs + cc1 * 8);
    __syncthreads();                       // compiler drains vmcnt before barrier
    bf16x8 a[4], b[4];
    #pragma unroll
    for (int mt = 0; mt < 4; ++mt)
      a[mt] = *(const bf16x8*)(As + (wm * 64 + mt * 16 + lrow) * 32 + quad * 8);
    #pragma unroll
    for (int nt = 0; nt < 4; ++nt)
      b[nt] = *(const bf16x8*)(Bs + (wn * 64 + nt * 16 + lrow) * 32 + quad * 8);
    #pragma unroll
    for (int mt = 0; mt < 4; ++mt)
      #pragma unroll
      for (int nt = 0; nt < 4; ++nt)
        acc[mt][nt] = __builtin_amdgcn_mfma_f32_16x16x32_bf16(
            a[mt], b[nt], acc[mt][nt], 0, 0, 0);
  }
  // C/D layout: col = lane&15, row = quad*4 + reg  [m89-verified]
  #pragma unroll
  for (int mt = 0; mt < 4; ++mt)
    #pragma unroll
    for (int nt = 0; nt < 4; ++nt) {
      int row = m0 + wm * 64 + mt * 16 + quad * 4;
      int col = n0 + wn * 64 + nt * 16 + lrow;
      float bias = Ubias[col];
      #pragma unroll
      for (int rr = 0; rr < 4; ++rr)
        T[(size_t)(row + rr) * D_DIM + col] = f2bf(acc[mt][nt][rr] + bias);
    }
}

// ---- GEMM2: out[b,x,y] = sum_k T[b,x,k]*Hbf[b,y,k] + linD[b,x] + linH[b,y] --
__global__ __launch_bounds__(256) void gemm2_kernel(
    const unsigned short* __restrict__ Tg,   // [32*512,1024]
    const unsigned short* __restrict__ Hbf,  // [32*512,1024]
    const float* __restrict__ linD, const float* __restrict__ linH,
    float* __restrict__ out) {               // [32,512,512]
  __shared__ __align__(16) unsigned short As[128 * 32];
  __shared__ __align__(16) unsigned short Bs[128 * 32];
  const int K = D_DIM;
  int tid = threadIdx.x;
  int lane = tid & 63, wave = tid >> 6;
  int quad = lane >> 4, lrow = lane & 15;
  int wm = wave >> 1, wn = wave & 1;
  int b = blockIdx.z;
  int m0 = blockIdx.y * 128, n0 = blockIdx.x * 128;
  const unsigned short* A = Tg + (size_t)b * 512 * D_DIM;
  const unsigned short* Bt = Hbf + (size_t)b * 512 * D_DIM;

  floatx4 acc[4][4] = {};

  int cc0 = tid, cc1 = tid + 256;
  int r0 = cc0 >> 2, kc0 = (cc0 & 3) * 8;
  int r1 = cc1 >> 2, kc1 = (cc1 & 3) * 8;
  const unsigned short* gA0 = A + (size_t)(m0 + r0) * K + kc0;
  const unsigned short* gA1 = A + (size_t)(m0 + r1) * K + kc1;
  const unsigned short* gB0 = Bt + (size_t)(n0 + r0) * K + kc0;
  const unsigned short* gB1 = Bt + (size_t)(n0 + r1) * K + kc1;

  for (int k0 = 0; k0 < K; k0 += 32) {
    __syncthreads();
    async_load16(gA0 + k0, As + cc0 * 8);
    async_load16(gA1 + k0, As + cc1 * 8);
    async_load16(gB0 + k0, Bs + cc0 * 8);
    async_load16(gB1 + k0, Bs + cc1 * 8);
    __syncthreads();
    bf16x8 a[4], bfr[4];
    #pragma unroll
    for (int mt = 0; mt < 4; ++mt)
      a[mt] = *(const bf16x8*)(As + (wm * 64 + mt * 16 + lrow) * 32 + quad * 8);
    #pragma unroll
    for (int nt = 0; nt < 4; ++nt)
      bfr[nt] = *(const bf16x8*)(Bs + (wn * 64 + nt * 16 + lrow) * 32 + quad * 8);
    #pragma unroll
    for (int mt = 0; mt < 4; ++mt)
      #pragma unroll
      for (int nt = 0; nt < 4; ++nt)
        acc[mt][nt] = __builtin_amdgcn_mfma_f32_16x16x32_bf16(
            a[mt], bfr[nt], acc[mt][nt], 0, 0, 0);
  }
  #pragma unroll
  for (int mt = 0; mt < 4; ++mt)
    #pragma unroll
    for (int nt = 0; nt < 4; ++nt) {
      int row = m0 + wm * 64 + mt * 16 + quad * 4;
      int col = n0 + wn * 64 + nt * 16 + lrow;
      float lh = linH[b * 512 + col];
      #pragma unroll
      for (int rr = 0; rr < 4; ++rr) {
        float v = acc[mt][nt][rr] + linD[b * 512 + row + rr] + lh;
        out[((size_t)b * 512 + row + rr) * 512 + col] = v;
      }
    }
}

extern "C" void kernel_launch(void* const* d_in, const int* in_sizes, int n_in,
                              void* d_out, int out_size, void* d_ws, size_t ws_size,
                              hipStream_t stream) {
  const float* D = (const float*)d_in[0];
  const float* H = (const float*)d_in[1];
  const float* U = (const float*)d_in[2];   // [1025,1024]
  const float* W = (const float*)d_in[3];   // [2049]
  float* out = (float*)d_out;

  char* ws = (char*)d_ws;
  unsigned short* Dbf = (unsigned short*)ws; ws += (size_t)ROWS * D_DIM * 2;   // 32 MB
  unsigned short* Hbf = (unsigned short*)ws; ws += (size_t)ROWS * D_DIM * 2;   // 32 MB
  unsigned short* Tbf = (unsigned short*)ws; ws += (size_t)ROWS * D_DIM * 2;   // 32 MB
  unsigned short* Ut  = (unsigned short*)ws; ws += (size_t)D_DIM * D_DIM * 2;  //  2 MB
  float* linD = (float*)ws;                  ws += (size_t)ROWS * 4;
  float* linH = (float*)ws;                  ws += (size_t)ROWS * 4;

  cast_rows_kernel<<<dim3(2 * ROWS), 256, 0, stream>>>(D, H, W, Dbf, Hbf, linD, linH);
  transU_kernel<<<dim3(32, 32), 256, 0, stream>>>(U, Ut);
  gemm1_kernel<<<dim3(8, 128), 256, 0, stream>>>(Dbf, Ut, U + (size_t)D_DIM * D_DIM, Tbf);
  gemm2_kernel<<<dim3(4, 4, 32), 256, 0, stream>>>(Tbf, Hbf, linD, linH, out);
}